// Round 6
// baseline (852.205 us; speedup 1.0000x reference)
//
#include <hip/hip_runtime.h>

// GraphAttentionEmbedding: 2x TransformerConv (PyG) on MI355X (gfx950).
// N=50000 nodes, E=400000 edges, IN=128, H1=8*16=128, OUT=128, EDIM=32.
// PROVEN (round 5): float inputs are fp32 (detect_fmt flipped behavior);
// therefore reference output dtype is fp32 -> d_out written as float.
// Internal pipeline: bf16 storage, fp32 accumulation (bf16 floor threshold).
// edge_index int32/int64 runtime-detected.

using u16 = unsigned short;
using u32 = unsigned int;

#define NODES 50000
#define EDGES 400000

typedef __attribute__((ext_vector_type(8))) short bf16x8;
typedef __attribute__((ext_vector_type(4))) float f32x4;

__device__ __forceinline__ float bflo(u32 u) { return __uint_as_float(u << 16); }
__device__ __forceinline__ float bfhi(u32 u) { return __uint_as_float(u & 0xffff0000u); }
__device__ __forceinline__ u16 f2bf(float f) {
    u32 u = __float_as_uint(f);
    u += 0x7fffu + ((u >> 16) & 1u);   // RNE
    return (u16)(u >> 16);
}
__device__ __forceinline__ u32 pack2(float a, float b) {
    return (u32)f2bf(a) | ((u32)f2bf(b) << 16);
}

// ---------------- diagnostic sentinel (fp32 out) ----------------------------
__global__ __launch_bounds__(256) void fill_sentinel(float* __restrict__ out, int n, float val) {
    int i = blockIdx.x * 256 + threadIdx.x;
    if (i < n) out[i] = val;
}

// ---------------- runtime format detection ----------------------------------
// flags[0]: 0 = float tensors are bf16, 1 = fp32 (expected: 1).
// flags[1]: 1 = edge_index int64, 0 = int32.
__global__ void detect_fmt(const u32* __restrict__ xw, const int* __restrict__ eraw,
                           int* __restrict__ flags) {
    if (threadIdx.x == 0 && blockIdx.x == 0) {
        int sane = 0;
        for (int i = 0; i < 64; ++i) {
            u32 e = (xw[i] >> 7) & 0xffu;
            if (e >= 90u && e <= 141u) sane++;
        }
        flags[0] = (sane == 64) ? 0 : 1;
        int any = 0;
        for (int i = 1; i < 256; i += 2) any |= eraw[i];
        flags[1] = (any == 0) ? 1 : 0;
    }
}

// ---------------- weight transpose+convert: W[128][128] -> Wt[128][128] bf16 -
struct TPtrs {
    const void* src[8];
    u16*        dst[8];
};

__global__ __launch_bounds__(256) void transpose_w(TPtrs P, const int* __restrict__ fmt) {
    int m = blockIdx.x;
    int f = *fmt;
    u16* d = P.dst[m];
    if (f) {
        const float* s = (const float*)P.src[m];
        for (int idx = threadIdx.x; idx < 128 * 128; idx += 256) {
            int k = idx >> 7, n = idx & 127;
            d[n * 128 + k] = f2bf(s[idx]);
        }
    } else {
        const u16* s = (const u16*)P.src[m];
        for (int idx = threadIdx.x; idx < 128 * 128; idx += 256) {
            int k = idx >> 7, n = idx & 127;
            d[n * 128 + k] = s[idx];
        }
    }
}

// ---------------- CSR build (by dst), shared across both layers -------------
__global__ __launch_bounds__(256) void count_deg(const int* __restrict__ raw,
                                                 const int* __restrict__ flags,
                                                 int* __restrict__ deg, int E) {
    int e = blockIdx.x * 256 + threadIdx.x;
    if (e < E) {
        int f = flags[1];
        int d = f ? raw[2 * (E + e)] : raw[E + e];
        if ((unsigned)d < (unsigned)NODES) atomicAdd(&deg[d], 1);
    }
}

__global__ __launch_bounds__(1024) void scan_kernel(const int* __restrict__ deg,
                                                    int* __restrict__ row_ptr, int n) {
    __shared__ int wsum[16];
    __shared__ int carry;
    int t = threadIdx.x, lane = t & 63, wv = t >> 6;
    if (t == 0) { row_ptr[0] = 0; carry = 0; }
    __syncthreads();
    for (int base = 0; base < n; base += 1024) {
        int i = base + t;
        int v = (i < n) ? deg[i] : 0;
        int x = v;
#pragma unroll
        for (int off = 1; off < 64; off <<= 1) {
            int y = __shfl_up(x, off, 64);
            if (lane >= off) x += y;
        }
        if (lane == 63) wsum[wv] = x;
        __syncthreads();
        if (t < 16) {
            int s = wsum[t];
#pragma unroll
            for (int off = 1; off < 16; off <<= 1) {
                int y = __shfl_up(s, off, 16);
                if (t >= off) s += y;
            }
            wsum[t] = s;
        }
        __syncthreads();
        int tot = carry + (wv > 0 ? wsum[wv - 1] : 0) + x;
        if (i < n) row_ptr[i + 1] = tot;
        __syncthreads();
        if (t == 1023) carry = tot;
        __syncthreads();
    }
}

__global__ __launch_bounds__(256) void copy_int(const int* __restrict__ a,
                                                int* __restrict__ b, int n) {
    int i = blockIdx.x * 256 + threadIdx.x;
    if (i < n) b[i] = a[i];
}

__global__ __launch_bounds__(256) void fill_csr(const int* __restrict__ raw,
                                                const int* __restrict__ flags,
                                                int* __restrict__ cursor,
                                                int* __restrict__ src_sorted,
                                                int* __restrict__ eid, int E) {
    int e = blockIdx.x * 256 + threadIdx.x;
    if (e < E) {
        int f = flags[1];
        int d = f ? raw[2 * (E + e)] : raw[E + e];
        int s = f ? raw[2 * e] : raw[e];
        if ((unsigned)d < (unsigned)NODES && (unsigned)s < (unsigned)NODES) {
            int pos = atomicAdd(&cursor[d], 1);
            if ((unsigned)pos < (unsigned)E) {
                src_sorted[pos] = s;
                eid[pos] = e;
            }
        }
    }
}

// ---------------- GEMM: O[M,128] = A[M,128] @ Wt[128,128]^T + bias ----------
// A: bf16, or fp32 when (a_raw && fmt==fp32) -- converted inline during LDS
// staging. Wt: always bf16 (pre-converted). bias: input dtype per fmt.
__global__ __launch_bounds__(256) void gemm128(
    const void* __restrict__ A, const int* __restrict__ flags, int a_raw,
    const u16* __restrict__ Wt0, const u16* __restrict__ Wt1,
    const u16* __restrict__ Wt2, const u16* __restrict__ Wt3,
    const void* __restrict__ b0, const void* __restrict__ b1,
    const void* __restrict__ b2, const void* __restrict__ b3,
    u16* __restrict__ O0, u16* __restrict__ O1,
    u16* __restrict__ O2, u16* __restrict__ O3,
    int M) {
    constexpr int K = 128;
    constexpr int PAD = K + 8;
    constexpr int KV = K / 8;
    __shared__ u16 Asl[64 * PAD];
    __shared__ u16 Bsl[128 * PAD];

    int f = flags[0];
    const u16* Wt; const void* bias; u16* O;
    switch (blockIdx.y) {
        case 0: Wt = Wt0; bias = b0; O = O0; break;
        case 1: Wt = Wt1; bias = b1; O = O1; break;
        case 2: Wt = Wt2; bias = b2; O = O2; break;
        default: Wt = Wt3; bias = b3; O = O3; break;
    }
    int m0 = blockIdx.x * 64;

    if (a_raw && f) {
        const float* Af = (const float*)A;
        for (int idx = threadIdx.x; idx < 64 * KV; idx += 256) {
            int r = idx / KV, cv = idx % KV;
            int gr = m0 + r;
            uint4 val = make_uint4(0, 0, 0, 0);
            if (gr < M) {
                const float* p = Af + (size_t)gr * K + cv * 8;
                float4 lo = *reinterpret_cast<const float4*>(p);
                float4 hi = *reinterpret_cast<const float4*>(p + 4);
                val = make_uint4(pack2(lo.x, lo.y), pack2(lo.z, lo.w),
                                 pack2(hi.x, hi.y), pack2(hi.z, hi.w));
            }
            *reinterpret_cast<uint4*>(&Asl[r * PAD + cv * 8]) = val;
        }
    } else {
        const u16* Ab = (const u16*)A;
        for (int idx = threadIdx.x; idx < 64 * KV; idx += 256) {
            int r = idx / KV, cv = idx % KV;
            int gr = m0 + r;
            uint4 val = make_uint4(0, 0, 0, 0);
            if (gr < M) val = *reinterpret_cast<const uint4*>(Ab + (size_t)gr * K + cv * 8);
            *reinterpret_cast<uint4*>(&Asl[r * PAD + cv * 8]) = val;
        }
    }
    for (int idx = threadIdx.x; idx < 128 * KV; idx += 256) {
        int r = idx / KV, cv = idx % KV;
        *reinterpret_cast<uint4*>(&Bsl[r * PAD + cv * 8]) =
            *reinterpret_cast<const uint4*>(Wt + r * K + cv * 8);
    }
    __syncthreads();

    int lane = threadIdx.x & 63, wv = threadIdx.x >> 6;
    int l15 = lane & 15;
    int kq = (lane >> 4) * 8;
    f32x4 acc[8] = {};
#pragma unroll
    for (int k0 = 0; k0 < K; k0 += 32) {
        bf16x8 af = *reinterpret_cast<const bf16x8*>(&Asl[(wv * 16 + l15) * PAD + k0 + kq]);
#pragma unroll
        for (int nt = 0; nt < 8; ++nt) {
            bf16x8 bfv = *reinterpret_cast<const bf16x8*>(&Bsl[(nt * 16 + l15) * PAD + k0 + kq]);
            acc[nt] = __builtin_amdgcn_mfma_f32_16x16x32_bf16(af, bfv, acc[nt], 0, 0, 0);
        }
    }

    int rbase = m0 + wv * 16 + (lane >> 4) * 4;   // C/D: row=quad*4+reg, col=lane&15
#pragma unroll
    for (int nt = 0; nt < 8; ++nt) {
        int col = nt * 16 + l15;
        float bb = 0.f;
        if (bias) bb = f ? ((const float*)bias)[col] : bflo((u32)((const u16*)bias)[col]);
#pragma unroll
        for (int r = 0; r < 4; ++r) {
            int m = rbase + r;
            if (m < M) O[(size_t)m * 128 + col] = f2bf(acc[nt][r] + bb);
        }
    }
}

// ---------------- per-node attention, online softmax, fused ee --------------
// One wave per dst node; lane owns channels {2*lane, 2*lane+1}.
// Q/K/V/SK internal bf16. EF/We read per detected input format.
// F32OUT=1 -> write fp32 (final output); 0 -> write bf16 (internal h).
template <int HEADS, int F32OUT>
__global__ __launch_bounds__(256) void attn_fused(
    const int* __restrict__ row_ptr, const int* __restrict__ srcs,
    const int* __restrict__ eids, const int* __restrict__ flags,
    const u16* __restrict__ Q, const u16* __restrict__ Kn,
    const u16* __restrict__ Vn, const void* __restrict__ EF,
    const void* __restrict__ We, const u16* __restrict__ SK,
    void* __restrict__ OUT, int nn) {
    int wv = threadIdx.x >> 6, lane = threadIdx.x & 63;
    int node = blockIdx.x * 4 + wv;
    if (node >= nn) return;
    int c0 = lane * 2;
    int f = flags[0];

    float wf0[32], wf1[32];
    if (f) {
        const float* Wef = (const float*)We;
#pragma unroll
        for (int d = 0; d < 32; ++d) {
            float2 w2 = *reinterpret_cast<const float2*>(Wef + d * 128 + c0);
            wf0[d] = w2.x; wf1[d] = w2.y;
        }
    } else {
        const u16* Web = (const u16*)We;
#pragma unroll
        for (int d = 0; d < 32; ++d) {
            u32 w = *reinterpret_cast<const u32*>(Web + d * 128 + c0);
            wf0[d] = bflo(w); wf1[d] = bfhi(w);
        }
    }

    u32 qb = *reinterpret_cast<const u32*>(Q + node * 128 + c0);
    float q0 = bflo(qb), q1 = bfhi(qb);

    int beg = row_ptr[node], end = row_ptr[node + 1];
    beg = min(max(beg, 0), EDGES);
    end = min(max(end, beg), EDGES);
    const float scale = (HEADS == 8) ? 0.25f : 0.08838834764831845f;  // 1/sqrt(C)
    constexpr int GRP = (HEADS == 8) ? 8 : 64;

    float m_run = -1e30f, l_run = 0.f, a0 = 0.f, a1 = 0.f;
    for (int i = beg; i < end; ++i) {
        int s = min(max(srcs[i], 0), NODES - 1);
        int e = min(max(eids[i], 0), EDGES - 1);
        u32 kb = *reinterpret_cast<const u32*>(Kn + s * 128 + c0);
        u32 vb = *reinterpret_cast<const u32*>(Vn + s * 128 + c0);

        float efv[32];
        if (f) {
            const float* eff = (const float*)EF + (size_t)e * 32;
#pragma unroll
            for (int t = 0; t < 8; ++t) {
                float4 q4 = *reinterpret_cast<const float4*>(eff + t * 4);
                efv[4 * t] = q4.x; efv[4 * t + 1] = q4.y;
                efv[4 * t + 2] = q4.z; efv[4 * t + 3] = q4.w;
            }
        } else {
            const uint4* efp = reinterpret_cast<const uint4*>((const u16*)EF + (size_t)e * 32);
            uint4 efa = efp[0], efb = efp[1], efc = efp[2], efd = efp[3];
            u32 efw[16] = {efa.x, efa.y, efa.z, efa.w, efb.x, efb.y, efb.z, efb.w,
                           efc.x, efc.y, efc.z, efc.w, efd.x, efd.y, efd.z, efd.w};
#pragma unroll
            for (int t = 0; t < 16; ++t) {
                efv[2 * t] = bflo(efw[t]);
                efv[2 * t + 1] = bfhi(efw[t]);
            }
        }

        float ee0 = 0.f, ee1 = 0.f;
#pragma unroll
        for (int t = 0; t < 32; ++t) {
            ee0 = fmaf(efv[t], wf0[t], ee0);
            ee1 = fmaf(efv[t], wf1[t], ee1);
        }

        float k0 = bflo(kb) + ee0, k1 = bfhi(kb) + ee1;
        float p = q0 * k0 + q1 * k1;
#pragma unroll
        for (int off = 1; off < GRP; off <<= 1) p += __shfl_xor(p, off, 64);
        float al = p * scale;
        float mn = fmaxf(m_run, al);
        float corr = __expf(m_run - mn);
        float w = __expf(al - mn);
        float v0 = bflo(vb) + ee0, v1 = bfhi(vb) + ee1;
        l_run = l_run * corr + w;
        a0 = a0 * corr + w * v0;
        a1 = a1 * corr + w * v1;
        m_run = mn;
    }
    float inv = 1.f / fmaxf(l_run, 1e-16f);
    u32 sb = *reinterpret_cast<const u32*>(SK + node * 128 + c0);
    float o0 = fmaxf(a0 * inv + bflo(sb), 0.f);
    float o1 = fmaxf(a1 * inv + bfhi(sb), 0.f);
    if (F32OUT) {
        *reinterpret_cast<float2*>((float*)OUT + (size_t)node * 128 + c0) = make_float2(o0, o1);
    } else {
        *reinterpret_cast<u32*>((u16*)OUT + (size_t)node * 128 + c0) = pack2(o0, o1);
    }
}

// ---------------------------------------------------------------------------
extern "C" void kernel_launch(void* const* d_in, const int* in_sizes, int n_in,
                              void* d_out, int out_size, void* d_ws, size_t ws_size,
                              hipStream_t stream) {
    const int N = NODES, E = EDGES;
    const void* x  = d_in[0];
    const int*  ei = (const int*)d_in[1];
    const void* ef = d_in[2];
    const void* Wq1 = d_in[3];  const void* bq1 = d_in[4];
    const void* Wk1 = d_in[5];  const void* bk1 = d_in[6];
    const void* Wv1 = d_in[7];  const void* bv1 = d_in[8];
    const void* We1 = d_in[9];
    const void* Ws1 = d_in[10]; const void* bs1 = d_in[11];
    const void* Wq2 = d_in[12]; const void* bq2 = d_in[13];
    const void* Wk2 = d_in[14]; const void* bk2 = d_in[15];
    const void* Wv2 = d_in[16]; const void* bv2 = d_in[17];
    const void* We2 = d_in[18];
    const void* Ws2 = d_in[19]; const void* bs2 = d_in[20];

    char* ws = (char*)d_ws;
    size_t off = 0;
    auto carve = [&](size_t bytes) -> void* {
        void* p = ws + off;
        off += (bytes + 255) & ~(size_t)255;
        return p;
    };

    u16* WtQ1 = (u16*)carve(128 * 128 * 2);
    u16* WtK1 = (u16*)carve(128 * 128 * 2);
    u16* WtV1 = (u16*)carve(128 * 128 * 2);
    u16* WtS1 = (u16*)carve(128 * 128 * 2);
    u16* WtQ2 = (u16*)carve(128 * 128 * 2);
    u16* WtK2 = (u16*)carve(128 * 128 * 2);
    u16* WtV2 = (u16*)carve(128 * 128 * 2);
    u16* WtS2 = (u16*)carve(128 * 128 * 2);
    int* flags   = (int*)carve(256);
    int* deg     = (int*)carve((size_t)N * 4);
    int* row_ptr = (int*)carve((size_t)(N + 1) * 4);
    int* cursor  = (int*)carve((size_t)N * 4);
    int* srcs    = (int*)carve((size_t)E * 4);
    int* eids    = (int*)carve((size_t)E * 4);
    u16* q  = (u16*)carve((size_t)N * 128 * 2);
    u16* k  = (u16*)carve((size_t)N * 128 * 2);
    u16* v  = (u16*)carve((size_t)N * 128 * 2);
    u16* sk = (u16*)carve((size_t)N * 128 * 2);
    u16* h  = (u16*)carve((size_t)N * 128 * 2);
    const size_t REQUIRED = off;   // ~68 MB (proven to fit: round 5 ran real path)

    if (ws_size < REQUIRED) {
        hipLaunchKernelGGL(fill_sentinel, dim3((out_size + 255) / 256), dim3(256), 0, stream,
                           (float*)d_out, out_size, 16.0f * (float)(ws_size >> 20));
        return;
    }

    hipLaunchKernelGGL(detect_fmt, dim3(1), dim3(64), 0, stream, (const u32*)x, ei, flags);

    TPtrs tp;
    tp.src[0] = Wq1; tp.dst[0] = WtQ1;
    tp.src[1] = Wk1; tp.dst[1] = WtK1;
    tp.src[2] = Wv1; tp.dst[2] = WtV1;
    tp.src[3] = Ws1; tp.dst[3] = WtS1;
    tp.src[4] = Wq2; tp.dst[4] = WtQ2;
    tp.src[5] = Wk2; tp.dst[5] = WtK2;
    tp.src[6] = Wv2; tp.dst[6] = WtV2;
    tp.src[7] = Ws2; tp.dst[7] = WtS2;
    hipLaunchKernelGGL(transpose_w, dim3(8), dim3(256), 0, stream, tp, flags);

    (void)hipMemsetAsync(deg, 0, (size_t)N * 4, stream);
    hipLaunchKernelGGL(count_deg, dim3((E + 255) / 256), dim3(256), 0, stream, ei, flags, deg, E);
    hipLaunchKernelGGL(scan_kernel, dim3(1), dim3(1024), 0, stream, deg, row_ptr, N);
    hipLaunchKernelGGL(copy_int, dim3((N + 255) / 256), dim3(256), 0, stream, row_ptr, cursor, N);
    hipLaunchKernelGGL(fill_csr, dim3((E + 255) / 256), dim3(256), 0, stream, ei, flags, cursor, srcs, eids, E);

    const int gN = (N + 63) / 64;   // 782

    // layer 1 (A = x, raw input dtype) -> h (bf16, internal)
    hipLaunchKernelGGL(gemm128, dim3(gN, 4), dim3(256), 0, stream,
                       x, flags, 1, WtQ1, WtK1, WtV1, WtS1,
                       bq1, bk1, bv1, bs1, q, k, v, sk, N);
    hipLaunchKernelGGL((attn_fused<8, 0>), dim3((N + 3) / 4), dim3(256), 0, stream,
                       row_ptr, srcs, eids, flags, q, k, v, ef, We1, sk, (void*)h, N);

    // layer 2 (A = h bf16; heads=1, C=128, mean==identity) -> d_out (fp32)
    hipLaunchKernelGGL(gemm128, dim3(gN, 4), dim3(256), 0, stream,
                       h, flags, 0, WtQ2, WtK2, WtV2, WtS2,
                       bq2, bk2, bv2, bs2, q, k, v, sk, N);
    hipLaunchKernelGGL((attn_fused<1, 1>), dim3((N + 3) / 4), dim3(256), 0, stream,
                       row_ptr, srcs, eids, flags, q, k, v, ef, We2, sk, d_out, N);
}

// Round 7
// 521.056 us; speedup vs baseline: 1.6355x; 1.6355x over previous
//
#include <hip/hip_runtime.h>

// GraphAttentionEmbedding: 2x TransformerConv (PyG) on MI355X (gfx950).
// N=50000, E=400000, IN=128, H1=8*16=128, OUT=128, EDIM=32.
// PROVEN: inputs fp32 (runtime-detected, dual path kept), output fp32.
// Internal: bf16 storage + fp32 accum. R6 profile: attn latency-bound
// (VALUBusy 24%, HBM 6.5%, 0 MFMA). R7: materialized CSR-ordered ee +
// 8-edge batched loads + no-max softmax (exact up to fp rounding).

using u16 = unsigned short;
using u32 = unsigned int;

#define NODES 50000
#define EDGES 400000

typedef __attribute__((ext_vector_type(8))) short bf16x8;
typedef __attribute__((ext_vector_type(4))) float f32x4;

__device__ __forceinline__ float bflo(u32 u) { return __uint_as_float(u << 16); }
__device__ __forceinline__ float bfhi(u32 u) { return __uint_as_float(u & 0xffff0000u); }
__device__ __forceinline__ u16 f2bf(float f) {
    u32 u = __float_as_uint(f);
    u += 0x7fffu + ((u >> 16) & 1u);   // RNE
    return (u16)(u >> 16);
}
__device__ __forceinline__ u32 pack2(float a, float b) {
    return (u32)f2bf(a) | ((u32)f2bf(b) << 16);
}

// ---------------- diagnostic sentinel (fp32 out) ----------------------------
__global__ __launch_bounds__(256) void fill_sentinel(float* __restrict__ out, int n, float val) {
    int i = blockIdx.x * 256 + threadIdx.x;
    if (i < n) out[i] = val;
}

// ---------------- runtime format detection ----------------------------------
__global__ void detect_fmt(const u32* __restrict__ xw, const int* __restrict__ eraw,
                           int* __restrict__ flags) {
    if (threadIdx.x == 0 && blockIdx.x == 0) {
        int sane = 0;
        for (int i = 0; i < 64; ++i) {
            u32 e = (xw[i] >> 7) & 0xffu;
            if (e >= 90u && e <= 141u) sane++;
        }
        flags[0] = (sane == 64) ? 0 : 1;   // 1 = fp32
        int any = 0;
        for (int i = 1; i < 256; i += 2) any |= eraw[i];
        flags[1] = (any == 0) ? 1 : 0;     // 1 = int64
    }
}

// ---------------- weight transpose+convert: W[K][128] -> Wt[128][K] bf16 ----
struct TPtrs {
    const void* src[10];
    u16*        dst[10];
    int         K[10];
};

__global__ __launch_bounds__(256) void transpose_w(TPtrs P, const int* __restrict__ fmt) {
    int m = blockIdx.x;
    int f = *fmt;
    int K = P.K[m];
    int total = K * 128;
    int quarter = total >> 2;
    u16* d = P.dst[m];
    int base = blockIdx.y * quarter;
    const float* sf = (const float*)P.src[m];
    const u16*   sb = (const u16*)P.src[m];
    for (int idx = base + threadIdx.x; idx < base + quarter; idx += 256) {
        int k = idx >> 7, n = idx & 127;
        d[n * K + k] = f ? f2bf(sf[idx]) : sb[idx];
    }
}

// ---------------- CSR build (by dst) ----------------------------------------
__global__ __launch_bounds__(256) void count_deg(const int* __restrict__ raw,
                                                 const int* __restrict__ flags,
                                                 int* __restrict__ deg, int E) {
    int e = blockIdx.x * 256 + threadIdx.x;
    if (e < E) {
        int f = flags[1];
        int d = f ? raw[2 * (E + e)] : raw[E + e];
        if ((unsigned)d < (unsigned)NODES) atomicAdd(&deg[d], 1);
    }
}

__global__ __launch_bounds__(1024) void scan_kernel(const int* __restrict__ deg,
                                                    int* __restrict__ row_ptr, int n) {
    __shared__ int wsum[16];
    __shared__ int carry;
    int t = threadIdx.x, lane = t & 63, wv = t >> 6;
    if (t == 0) { row_ptr[0] = 0; carry = 0; }
    __syncthreads();
    for (int base = 0; base < n; base += 1024) {
        int i = base + t;
        int v = (i < n) ? deg[i] : 0;
        int x = v;
#pragma unroll
        for (int off = 1; off < 64; off <<= 1) {
            int y = __shfl_up(x, off, 64);
            if (lane >= off) x += y;
        }
        if (lane == 63) wsum[wv] = x;
        __syncthreads();
        if (t < 16) {
            int s = wsum[t];
#pragma unroll
            for (int off = 1; off < 16; off <<= 1) {
                int y = __shfl_up(s, off, 16);
                if (t >= off) s += y;
            }
            wsum[t] = s;
        }
        __syncthreads();
        int tot = carry + (wv > 0 ? wsum[wv - 1] : 0) + x;
        if (i < n) row_ptr[i + 1] = tot;
        __syncthreads();
        if (t == 1023) carry = tot;
        __syncthreads();
    }
}

__global__ __launch_bounds__(256) void copy_int(const int* __restrict__ a,
                                                int* __restrict__ b, int n) {
    int i = blockIdx.x * 256 + threadIdx.x;
    if (i < n) b[i] = a[i];
}

// writes se[pos] = {src, edge_id} sorted by dst
__global__ __launch_bounds__(256) void fill_csr(const int* __restrict__ raw,
                                                const int* __restrict__ flags,
                                                int* __restrict__ cursor,
                                                int2* __restrict__ se, int E) {
    int e = blockIdx.x * 256 + threadIdx.x;
    if (e < E) {
        int f = flags[1];
        int d = f ? raw[2 * (E + e)] : raw[E + e];
        int s = f ? raw[2 * e] : raw[e];
        if ((unsigned)d < (unsigned)NODES && (unsigned)s < (unsigned)NODES) {
            int pos = atomicAdd(&cursor[d], 1);
            if ((unsigned)pos < (unsigned)E) se[pos] = make_int2(s, e);
        }
    }
}

// ---------------- GEMM: O[M,128] = A[M,128] @ Wt[128,128]^T + bias ----------
__global__ __launch_bounds__(256) void gemm128(
    const void* __restrict__ A, const int* __restrict__ flags, int a_raw,
    const u16* __restrict__ Wt0, const u16* __restrict__ Wt1,
    const u16* __restrict__ Wt2, const u16* __restrict__ Wt3,
    const void* __restrict__ b0, const void* __restrict__ b1,
    const void* __restrict__ b2, const void* __restrict__ b3,
    u16* __restrict__ O0, u16* __restrict__ O1,
    u16* __restrict__ O2, u16* __restrict__ O3,
    int M) {
    constexpr int K = 128;
    constexpr int PAD = K + 8;
    constexpr int KV = K / 8;
    __shared__ u16 Asl[64 * PAD];
    __shared__ u16 Bsl[128 * PAD];

    int f = flags[0];
    const u16* Wt; const void* bias; u16* O;
    switch (blockIdx.y) {
        case 0: Wt = Wt0; bias = b0; O = O0; break;
        case 1: Wt = Wt1; bias = b1; O = O1; break;
        case 2: Wt = Wt2; bias = b2; O = O2; break;
        default: Wt = Wt3; bias = b3; O = O3; break;
    }
    int m0 = blockIdx.x * 64;

    if (a_raw && f) {
        const float* Af = (const float*)A;
        for (int idx = threadIdx.x; idx < 64 * KV; idx += 256) {
            int r = idx / KV, cv = idx % KV;
            int gr = m0 + r;
            uint4 val = make_uint4(0, 0, 0, 0);
            if (gr < M) {
                const float* p = Af + (size_t)gr * K + cv * 8;
                float4 lo = *reinterpret_cast<const float4*>(p);
                float4 hi = *reinterpret_cast<const float4*>(p + 4);
                val = make_uint4(pack2(lo.x, lo.y), pack2(lo.z, lo.w),
                                 pack2(hi.x, hi.y), pack2(hi.z, hi.w));
            }
            *reinterpret_cast<uint4*>(&Asl[r * PAD + cv * 8]) = val;
        }
    } else {
        const u16* Ab = (const u16*)A;
        for (int idx = threadIdx.x; idx < 64 * KV; idx += 256) {
            int r = idx / KV, cv = idx % KV;
            int gr = m0 + r;
            uint4 val = make_uint4(0, 0, 0, 0);
            if (gr < M) val = *reinterpret_cast<const uint4*>(Ab + (size_t)gr * K + cv * 8);
            *reinterpret_cast<uint4*>(&Asl[r * PAD + cv * 8]) = val;
        }
    }
    for (int idx = threadIdx.x; idx < 128 * KV; idx += 256) {
        int r = idx / KV, cv = idx % KV;
        *reinterpret_cast<uint4*>(&Bsl[r * PAD + cv * 8]) =
            *reinterpret_cast<const uint4*>(Wt + r * K + cv * 8);
    }
    __syncthreads();

    int lane = threadIdx.x & 63, wv = threadIdx.x >> 6;
    int l15 = lane & 15;
    int kq = (lane >> 4) * 8;
    f32x4 acc[8] = {};
#pragma unroll
    for (int k0 = 0; k0 < K; k0 += 32) {
        bf16x8 af = *reinterpret_cast<const bf16x8*>(&Asl[(wv * 16 + l15) * PAD + k0 + kq]);
#pragma unroll
        for (int nt = 0; nt < 8; ++nt) {
            bf16x8 bfv = *reinterpret_cast<const bf16x8*>(&Bsl[(nt * 16 + l15) * PAD + k0 + kq]);
            acc[nt] = __builtin_amdgcn_mfma_f32_16x16x32_bf16(af, bfv, acc[nt], 0, 0, 0);
        }
    }

    int rbase = m0 + wv * 16 + (lane >> 4) * 4;   // C/D: row=quad*4+reg, col=lane&15
#pragma unroll
    for (int nt = 0; nt < 8; ++nt) {
        int col = nt * 16 + l15;
        float bb = 0.f;
        if (bias) bb = f ? ((const float*)bias)[col] : bflo((u32)((const u16*)bias)[col]);
#pragma unroll
        for (int r = 0; r < 4; ++r) {
            int m = rbase + r;
            if (m < M) O[(size_t)m * 128 + col] = f2bf(acc[nt][r] + bb);
        }
    }
}

// ---------------- ee GEMM in CSR order: EE[pos,128] = EF[se[pos].y] @ We ----
// Gathers EF rows by edge id, writes ee rows CONTIGUOUS in CSR position so
// the attention loop streams them. K=32 -> single MFMA k-step.
__global__ __launch_bounds__(256) void gemm_ee(
    const int2* __restrict__ se, const void* __restrict__ EF,
    const u16* __restrict__ WtE /*[128][32] bf16*/, const int* __restrict__ flags,
    u16* __restrict__ EE, int Etot) {
    constexpr int PAD = 40;
    __shared__ u16 Asl[64 * PAD];
    __shared__ u16 Bsl[128 * PAD];
    int p0 = blockIdx.x * 64;
    int f = flags[0];

    {
        int r = threadIdx.x >> 2, seg = threadIdx.x & 3;
        int p = p0 + r;
        int e = (p < Etot) ? se[p].y : 0;
        uint4 val;
        if (f) {
            const float* src = (const float*)EF + (size_t)e * 32 + seg * 8;
            float4 lo = *reinterpret_cast<const float4*>(src);
            float4 hi = *reinterpret_cast<const float4*>(src + 4);
            val = make_uint4(pack2(lo.x, lo.y), pack2(lo.z, lo.w),
                             pack2(hi.x, hi.y), pack2(hi.z, hi.w));
        } else {
            val = *reinterpret_cast<const uint4*>((const u16*)EF + (size_t)e * 32 + seg * 8);
        }
        *reinterpret_cast<uint4*>(&Asl[r * PAD + seg * 8]) = val;
    }
    for (int idx = threadIdx.x; idx < 128 * 4; idx += 256) {
        int r = idx >> 2, seg = idx & 3;
        *reinterpret_cast<uint4*>(&Bsl[r * PAD + seg * 8]) =
            *reinterpret_cast<const uint4*>(WtE + r * 32 + seg * 8);
    }
    __syncthreads();

    int lane = threadIdx.x & 63, wv = threadIdx.x >> 6;
    int l15 = lane & 15;
    int kq = (lane >> 4) * 8;
    bf16x8 af = *reinterpret_cast<const bf16x8*>(&Asl[(wv * 16 + l15) * PAD + kq]);
    f32x4 acc[8] = {};
#pragma unroll
    for (int nt = 0; nt < 8; ++nt) {
        bf16x8 bfv = *reinterpret_cast<const bf16x8*>(&Bsl[(nt * 16 + l15) * PAD + kq]);
        acc[nt] = __builtin_amdgcn_mfma_f32_16x16x32_bf16(af, bfv, acc[nt], 0, 0, 0);
    }
    int rbase = p0 + wv * 16 + (lane >> 4) * 4;
#pragma unroll
    for (int nt = 0; nt < 8; ++nt) {
        int col = nt * 16 + l15;
#pragma unroll
        for (int r = 0; r < 4; ++r) {
            int p = rbase + r;
            if (p < Etot) EE[(size_t)p * 128 + col] = f2bf(acc[nt][r]);
        }
    }
}

// ---------------- attention: exp (no max), batched-8 loads ------------------
// One wave per dst node; lane owns channels {2*lane, 2*lane+1}.
// MAT=1: ee pre-materialized in CSR order (streaming read).
// MAT=0: fused ee dot (fallback when workspace is small).
template <int HEADS, int F32OUT, int MAT>
__global__ __launch_bounds__(256) void attn_kernel(
    const int* __restrict__ row_ptr, const int2* __restrict__ se,
    const int* __restrict__ flags,
    const u16* __restrict__ Q, const u16* __restrict__ Kn,
    const u16* __restrict__ Vn, const u16* __restrict__ EE,
    const void* __restrict__ EF, const void* __restrict__ We,
    const u16* __restrict__ SK, void* __restrict__ OUT, int nn) {
    int wv = threadIdx.x >> 6, lane = threadIdx.x & 63;
    int node = blockIdx.x * 4 + wv;
    if (node >= nn) return;
    int c0 = lane * 2;
    int f = flags[0];

    u32 qb = *reinterpret_cast<const u32*>(Q + (size_t)node * 128 + c0);
    float q0 = bflo(qb), q1 = bfhi(qb);

    int beg = row_ptr[node], end = row_ptr[node + 1];
    const float scale = (HEADS == 8) ? 0.25f : 0.08838834764831845f;  // 1/sqrt(C)
    constexpr int GRP = (HEADS == 8) ? 8 : 64;

    float l_run = 0.f, a0 = 0.f, a1 = 0.f;

    if (MAT) {
        int i = beg;
        while (i < end) {
            int cnt = end - i;
            if (cnt > 8) cnt = 8;
            int sA[8];
#pragma unroll
            for (int j = 0; j < 8; ++j) {
                int idx = i + (j < cnt ? j : cnt - 1);
                sA[j] = se[idx].x;
            }
            u32 kb[8], vb[8], eb[8];
#pragma unroll
            for (int j = 0; j < 8; ++j) {
                int idx = i + (j < cnt ? j : cnt - 1);
                kb[j] = *reinterpret_cast<const u32*>(Kn + (size_t)sA[j] * 128 + c0);
                vb[j] = *reinterpret_cast<const u32*>(Vn + (size_t)sA[j] * 128 + c0);
                eb[j] = *reinterpret_cast<const u32*>(EE + (size_t)idx * 128 + c0);
            }
#pragma unroll
            for (int j = 0; j < 8; ++j) {
                if (j < cnt) {
                    float e0 = bflo(eb[j]), e1 = bfhi(eb[j]);
                    float k0 = bflo(kb[j]) + e0, k1 = bfhi(kb[j]) + e1;
                    float p = q0 * k0 + q1 * k1;
#pragma unroll
                    for (int off = 1; off < GRP; off <<= 1) p += __shfl_xor(p, off, 64);
                    float w = __expf(p * scale);
                    float v0 = bflo(vb[j]) + e0, v1 = bfhi(vb[j]) + e1;
                    l_run += w;
                    a0 = fmaf(w, v0, a0);
                    a1 = fmaf(w, v1, a1);
                }
            }
            i += cnt;
        }
    } else {
        float wf0[32], wf1[32];
        if (f) {
            const float* Wef = (const float*)We;
#pragma unroll
            for (int d = 0; d < 32; ++d) {
                float2 w2 = *reinterpret_cast<const float2*>(Wef + d * 128 + c0);
                wf0[d] = w2.x; wf1[d] = w2.y;
            }
        } else {
            const u16* Web = (const u16*)We;
#pragma unroll
            for (int d = 0; d < 32; ++d) {
                u32 w = *reinterpret_cast<const u32*>(Web + d * 128 + c0);
                wf0[d] = bflo(w); wf1[d] = bfhi(w);
            }
        }
        for (int i = beg; i < end; ++i) {
            int2 p2 = se[i];
            int s = p2.x, e = p2.y;
            u32 kb = *reinterpret_cast<const u32*>(Kn + (size_t)s * 128 + c0);
            u32 vb = *reinterpret_cast<const u32*>(Vn + (size_t)s * 128 + c0);
            float efv[32];
            if (f) {
                const float* eff = (const float*)EF + (size_t)e * 32;
#pragma unroll
                for (int t = 0; t < 8; ++t) {
                    float4 q4 = *reinterpret_cast<const float4*>(eff + t * 4);
                    efv[4 * t] = q4.x; efv[4 * t + 1] = q4.y;
                    efv[4 * t + 2] = q4.z; efv[4 * t + 3] = q4.w;
                }
            } else {
                const uint4* efp = reinterpret_cast<const uint4*>((const u16*)EF + (size_t)e * 32);
                uint4 efa = efp[0], efb2 = efp[1], efc = efp[2], efd = efp[3];
                u32 efw[16] = {efa.x, efa.y, efa.z, efa.w, efb2.x, efb2.y, efb2.z, efb2.w,
                               efc.x, efc.y, efc.z, efc.w, efd.x, efd.y, efd.z, efd.w};
#pragma unroll
                for (int t = 0; t < 16; ++t) {
                    efv[2 * t] = bflo(efw[t]);
                    efv[2 * t + 1] = bfhi(efw[t]);
                }
            }
            float ee0 = 0.f, ee1 = 0.f;
#pragma unroll
            for (int t = 0; t < 32; ++t) {
                ee0 = fmaf(efv[t], wf0[t], ee0);
                ee1 = fmaf(efv[t], wf1[t], ee1);
            }
            float k0 = bflo(kb) + ee0, k1 = bfhi(kb) + ee1;
            float p = q0 * k0 + q1 * k1;
#pragma unroll
            for (int off = 1; off < GRP; off <<= 1) p += __shfl_xor(p, off, 64);
            float w = __expf(p * scale);
            float v0 = bflo(vb) + ee0, v1 = bfhi(vb) + ee1;
            l_run += w;
            a0 = fmaf(w, v0, a0);
            a1 = fmaf(w, v1, a1);
        }
    }

    float inv = 1.f / fmaxf(l_run, 1e-16f);
    u32 sb = *reinterpret_cast<const u32*>(SK + (size_t)node * 128 + c0);
    float o0 = fmaxf(a0 * inv + bflo(sb), 0.f);
    float o1 = fmaxf(a1 * inv + bfhi(sb), 0.f);
    if (F32OUT) {
        *reinterpret_cast<float2*>((float*)OUT + (size_t)node * 128 + c0) = make_float2(o0, o1);
    } else {
        *reinterpret_cast<u32*>((u16*)OUT + (size_t)node * 128 + c0) = pack2(o0, o1);
    }
}

// ---------------------------------------------------------------------------
extern "C" void kernel_launch(void* const* d_in, const int* in_sizes, int n_in,
                              void* d_out, int out_size, void* d_ws, size_t ws_size,
                              hipStream_t stream) {
    const int N = NODES, E = EDGES;
    const void* x  = d_in[0];
    const int*  ei = (const int*)d_in[1];
    const void* ef = d_in[2];
    const void* Wq1 = d_in[3];  const void* bq1 = d_in[4];
    const void* Wk1 = d_in[5];  const void* bk1 = d_in[6];
    const void* Wv1 = d_in[7];  const void* bv1 = d_in[8];
    const void* We1 = d_in[9];
    const void* Ws1 = d_in[10]; const void* bs1 = d_in[11];
    const void* Wq2 = d_in[12]; const void* bq2 = d_in[13];
    const void* Wk2 = d_in[14]; const void* bk2 = d_in[15];
    const void* Wv2 = d_in[16]; const void* bv2 = d_in[17];
    const void* We2 = d_in[18];
    const void* Ws2 = d_in[19]; const void* bs2 = d_in[20];

    char* ws = (char*)d_ws;
    size_t off = 0;
    auto carve = [&](size_t bytes) -> void* {
        void* p = ws + off;
        off += (bytes + 255) & ~(size_t)255;
        return p;
    };

    u16* WtQ1 = (u16*)carve(128 * 128 * 2);
    u16* WtK1 = (u16*)carve(128 * 128 * 2);
    u16* WtV1 = (u16*)carve(128 * 128 * 2);
    u16* WtS1 = (u16*)carve(128 * 128 * 2);
    u16* WtQ2 = (u16*)carve(128 * 128 * 2);
    u16* WtK2 = (u16*)carve(128 * 128 * 2);
    u16* WtV2 = (u16*)carve(128 * 128 * 2);
    u16* WtS2 = (u16*)carve(128 * 128 * 2);
    u16* WtE1 = (u16*)carve(128 * 32 * 2);
    u16* WtE2 = (u16*)carve(128 * 32 * 2);
    int* flags   = (int*)carve(256);
    int* deg     = (int*)carve((size_t)N * 4);
    int* row_ptr = (int*)carve((size_t)(N + 1) * 4);
    int* cursor  = (int*)carve((size_t)N * 4);
    int2* se     = (int2*)carve((size_t)E * 8);
    u16* q  = (u16*)carve((size_t)N * 128 * 2);
    u16* k  = (u16*)carve((size_t)N * 128 * 2);
    u16* v  = (u16*)carve((size_t)N * 128 * 2);
    u16* sk = (u16*)carve((size_t)N * 128 * 2);
    u16* h  = (u16*)carve((size_t)N * 128 * 2);
    const size_t REQ_BASE = off;                       // ~68 MB (fits: R5/R6 ran)
    u16* ee = (u16*)carve((size_t)E * 128 * 2);        // +102.4 MB, reused per layer
    const size_t REQ_BIG = off;                        // ~171 MB
    const bool MATOK = (ws_size >= REQ_BIG);

    if (ws_size < REQ_BASE) {
        hipLaunchKernelGGL(fill_sentinel, dim3((out_size + 255) / 256), dim3(256), 0, stream,
                           (float*)d_out, out_size, 16.0f * (float)(ws_size >> 20));
        return;
    }

    hipLaunchKernelGGL(detect_fmt, dim3(1), dim3(64), 0, stream, (const u32*)x, ei, flags);

    TPtrs tp;
    tp.src[0] = Wq1; tp.dst[0] = WtQ1; tp.K[0] = 128;
    tp.src[1] = Wk1; tp.dst[1] = WtK1; tp.K[1] = 128;
    tp.src[2] = Wv1; tp.dst[2] = WtV1; tp.K[2] = 128;
    tp.src[3] = Ws1; tp.dst[3] = WtS1; tp.K[3] = 128;
    tp.src[4] = Wq2; tp.dst[4] = WtQ2; tp.K[4] = 128;
    tp.src[5] = Wk2; tp.dst[5] = WtK2; tp.K[5] = 128;
    tp.src[6] = Wv2; tp.dst[6] = WtV2; tp.K[6] = 128;
    tp.src[7] = Ws2; tp.dst[7] = WtS2; tp.K[7] = 128;
    tp.src[8] = We1; tp.dst[8] = WtE1; tp.K[8] = 32;
    tp.src[9] = We2; tp.dst[9] = WtE2; tp.K[9] = 32;
    hipLaunchKernelGGL(transpose_w, dim3(10, 4), dim3(256), 0, stream, tp, flags);

    (void)hipMemsetAsync(deg, 0, (size_t)N * 4, stream);
    hipLaunchKernelGGL(count_deg, dim3((E + 255) / 256), dim3(256), 0, stream, ei, flags, deg, E);
    hipLaunchKernelGGL(scan_kernel, dim3(1), dim3(1024), 0, stream, deg, row_ptr, N);
    hipLaunchKernelGGL(copy_int, dim3((N + 255) / 256), dim3(256), 0, stream, row_ptr, cursor, N);
    hipLaunchKernelGGL(fill_csr, dim3((E + 255) / 256), dim3(256), 0, stream, ei, flags, cursor, se, E);

    const int gN = (N + 63) / 64;   // 782
    const int gE = E / 64;          // 6250
    const int gA = (N + 3) / 4;     // 12500

    // layer 1
    hipLaunchKernelGGL(gemm128, dim3(gN, 4), dim3(256), 0, stream,
                       x, flags, 1, WtQ1, WtK1, WtV1, WtS1,
                       bq1, bk1, bv1, bs1, q, k, v, sk, N);
    if (MATOK) {
        hipLaunchKernelGGL(gemm_ee, dim3(gE), dim3(256), 0, stream, se, ef, WtE1, flags, ee, E);
        hipLaunchKernelGGL((attn_kernel<8, 0, 1>), dim3(gA), dim3(256), 0, stream,
                           row_ptr, se, flags, q, k, v, ee, ef, We1, sk, (void*)h, N);
    } else {
        hipLaunchKernelGGL((attn_kernel<8, 0, 0>), dim3(gA), dim3(256), 0, stream,
                           row_ptr, se, flags, q, k, v, (const u16*)nullptr, ef, We1, sk, (void*)h, N);
    }

    // layer 2
    hipLaunchKernelGGL(gemm128, dim3(gN, 4), dim3(256), 0, stream,
                       h, flags, 0, WtQ2, WtK2, WtV2, WtS2,
                       bq2, bk2, bv2, bs2, q, k, v, sk, N);
    if (MATOK) {
        hipLaunchKernelGGL(gemm_ee, dim3(gE), dim3(256), 0, stream, se, ef, WtE2, flags, ee, E);
        hipLaunchKernelGGL((attn_kernel<1, 1, 1>), dim3(gA), dim3(256), 0, stream,
                           row_ptr, se, flags, q, k, v, ee, ef, We2, sk, d_out, N);
    } else {
        hipLaunchKernelGGL((attn_kernel<1, 1, 0>), dim3(gA), dim3(256), 0, stream,
                           row_ptr, se, flags, q, k, v, (const u16*)nullptr, ef, We2, sk, d_out, N);
    }
}